// Round 1
// baseline (248.850 us; speedup 1.0000x reference)
//
#include <hip/hip_runtime.h>

// Shapes fixed by the reference: B=8, C=128, H=W=64 -> S=4096. All I/O fp32.
#define BB 8
#define CC 128
#define SS 4096
#define KT 64             // kv tile per iteration
#define SCALE 0.015625f   // 1/sqrt(H*W) = 1/64

typedef __attribute__((ext_vector_type(8))) short sh8;   // 8 bf16 (MFMA A/B frag)
typedef __attribute__((ext_vector_type(4))) float f32x4; // MFMA C/D frag

__device__ __forceinline__ float b2f(unsigned short u) {
    union { unsigned int i; float f; } x; x.i = ((unsigned int)u) << 16; return x.f;
}
__device__ __forceinline__ unsigned short f2b(float f) {  // RNE (used in cvt)
    union { float f; unsigned int i; } x; x.f = f;
    unsigned int r = x.i + 0x7fff + ((x.i >> 16) & 1);
    return (unsigned short)(r >> 16);
}
__device__ __forceinline__ unsigned short rhu(float f) {  // round-half-up, 2 VALU
    union { float f; unsigned int i; } x; x.f = f;
    return (unsigned short)((x.i + 0x8000) >> 16);
}

// async 16B global->LDS DMA (lane i writes lds_base + i*16; LDS base wave-uniform)
__device__ __forceinline__ void dma16(const void* g, void* l) {
    __builtin_amdgcn_global_load_lds((const __attribute__((address_space(1))) void*)g,
                                     (__attribute__((address_space(3))) void*)l,
                                     16, 0, 0);
}

// ---------------------------------------------------------------------------
// cvt: V fp32->bf16 (layout preserved) + W/bias fp32->bf16 (one-time).
// blocks 0..511: V. blocks 512..519: Wq|Wk|bq|bk concat (33024 elems).
// ---------------------------------------------------------------------------
__global__ __launch_bounds__(256) void cvt_kernel(
    const float* __restrict__ vimg,
    const float* __restrict__ Wq, const float* __restrict__ Wk,
    const float* __restrict__ bq, const float* __restrict__ bk,
    unsigned short* __restrict__ Vbuf,
    unsigned short* __restrict__ Wqb, unsigned short* __restrict__ Wkb,
    unsigned short* __restrict__ bqb, unsigned short* __restrict__ bkb)
{
    const int bx = blockIdx.x, tid = threadIdx.x;
    if (bx < 512) {
        const size_t base = (size_t)bx * 8192 + tid * 4;
        #pragma unroll
        for (int it = 0; it < 8; ++it) {
            const size_t i = base + (size_t)it * 1024;
            float4 v = *(const float4*)(vimg + i);
            ushort4 o;
            o.x = f2b(v.x); o.y = f2b(v.y); o.z = f2b(v.z); o.w = f2b(v.w);
            *(ushort4*)(Vbuf + i) = o;
        }
    } else {
        const int w = bx - 512;  // 0..7
        for (int e = w * 256 + tid; e < 33024; e += 2048) {
            float v; unsigned short* dst;
            if (e < 16384)      { v = Wq[e];         dst = Wqb + e; }
            else if (e < 32768) { v = Wk[e - 16384]; dst = Wkb + (e - 16384); }
            else if (e < 32896) { v = bq[e - 32768]; dst = bqb + (e - 32768); }
            else                { v = bk[e - 32896]; dst = bkb + (e - 32896); }
            *dst = f2b(v);
        }
    }
}

// ---------------------------------------------------------------------------
// Projection with LDS-transposed img staging (coalesced float4 global loads).
// outTok[b][s][o] = sum_c img[b][c][s] * W[o][c] + bias[o]
// grid=(64, 8, 2): z=0 -> Q, z=1 -> K.
// ---------------------------------------------------------------------------
__global__ __launch_bounds__(256) void proj_kernel(
    const float* __restrict__ qimg, const float* __restrict__ kimg,
    const unsigned short* __restrict__ Wqb, const unsigned short* __restrict__ Wkb,
    const unsigned short* __restrict__ bqb, const unsigned short* __restrict__ bkb,
    unsigned short* __restrict__ Qbuf, unsigned short* __restrict__ Kbuf)
{
    __shared__ float ilds[128 * 69];   // 128 chans x (64 tokens + 5 pad) = 35,328 B

    const int z = blockIdx.z;
    const float* img = (z == 0) ? qimg : kimg;
    const unsigned short* Wb = (z == 0) ? Wqb : Wkb;
    const unsigned short* bias = (z == 0) ? bqb : bkb;
    unsigned short* outTok = (z == 0) ? Qbuf : Kbuf;

    const int tid  = threadIdx.x;
    const int wave = tid >> 6;
    const int lane = tid & 63;
    const int l15  = lane & 15;
    const int quad = lane >> 4;
    const int b     = blockIdx.y;
    const int stile = blockIdx.x;

    // stage 128x64 fp32 tile, coalesced (64B contiguous per 16 lanes)
    const float* gbase = img + (size_t)b * CC * SS + stile * 64;
    #pragma unroll
    for (int i = 0; i < 8; ++i) {
        const int l = tid + 256 * i;          // 0..2047
        const int row = l >> 4, col = (l & 15) * 4;
        float4 v = *(const float4*)(gbase + (size_t)row * SS + col);
        float* d = ilds + row * 69 + col;
        d[0] = v.x; d[1] = v.y; d[2] = v.z; d[3] = v.w;
    }
    __syncthreads();

    // A-frags from LDS: A[m=l15][k=32kk+quad*8+j] = img[c=k][token]
    const int tcol = wave * 16 + l15;
    sh8 a[4];
    #pragma unroll
    for (int kk = 0; kk < 4; ++kk)
        #pragma unroll
        for (int j = 0; j < 8; ++j)
            a[kk][j] = (short)rhu(ilds[(32 * kk + quad * 8 + j) * 69 + tcol]);

    f32x4 acc[8];
    #pragma unroll
    for (int nt = 0; nt < 8; ++nt) acc[nt] = (f32x4){0.f, 0.f, 0.f, 0.f};

    #pragma unroll
    for (int nt = 0; nt < 8; ++nt) {
        const unsigned short* wp = Wb + (size_t)(16 * nt + l15) * CC + quad * 8;
        #pragma unroll
        for (int kk = 0; kk < 4; ++kk) {
            sh8 bf = *(const sh8*)(wp + 32 * kk);
            acc[nt] = __builtin_amdgcn_mfma_f32_16x16x32_bf16(a[kk], bf, acc[nt], 0, 0, 0);
        }
    }

    #pragma unroll
    for (int nt = 0; nt < 8; ++nt) {
        const int o = 16 * nt + l15;
        const float bv = b2f(bias[o]);
        #pragma unroll
        for (int r = 0; r < 4; ++r) {
            const int s = stile * 64 + wave * 16 + quad * 4 + r;
            outTok[((size_t)b * SS + s) * CC + o] = f2b(acc[nt][r] + bv);
        }
    }
}

// ---------------------------------------------------------------------------
// Flash attention, M=32 queries/wave (2x K/V-frag reuse vs M=16).
// 4 waves x 32 q = 128 q/block; grid = 256 blocks = 1/CU; batch = wgid&7 so
// each XCD's L2 holds exactly one batch's K/V (2 MB).
// LDS (81,920 B):
//   [0,16384)       K buf0 : 64 rows(token) x 256 B, chunk swizzle ^(row&7)
//   [16384,32768)   K buf1
//   [32768,49152)   V buf0 : 128 rows(chan) x 128 B, chunk swizzle ^(row&7)
//   [49152,65536)   V buf1
//   [65536,81920)   P : 4 waves x (32 rows x 128 B), chunk swizzle ^(row&7)
//   epilogue: oLds float[128][129] (66,048 B) aliases front after barrier.
// Per iter: [waitcnt vmcnt(0); s_barrier] -> issue DMA(next)->other buf ->
//   QK (16 frag loads / 32 MFMA) -> softmax/P -> PV (20 loads / 32 MFMA).
// DMA has the whole compute phase (~1.5 kcy) to land from L2.
// ---------------------------------------------------------------------------
__global__ __launch_bounds__(256, 1) void attn_kernel(
    const unsigned short* __restrict__ Qbuf,  // (B,S,C) bf16 token-major
    const unsigned short* __restrict__ Kbuf,  // (B,S,C) bf16 token-major
    const unsigned short* __restrict__ Vbuf,  // (B,C,S) bf16 channel-major
    float* __restrict__ out)                  // (B,C,S) fp32 channel-major
{
    __shared__ __align__(16) unsigned char smem[81920];

    const int tid  = threadIdx.x;
    const int wave = tid >> 6;
    const int lane = tid & 63;
    const int l15  = lane & 15;
    const int quad = lane >> 4;
    const int wgid  = blockIdx.x;
    const int b     = wgid & 7;            // batch == XCD (wgid%8 heuristic)
    const int qtile = wgid >> 3;           // 0..31, 128 queries each
    const int qbase = qtile * 128 + wave * 32;

    unsigned char* pw = smem + 65536 + wave * 4096;  // this wave's P (32 x 128 B)

    const unsigned short* kbp = Kbuf + (size_t)b * SS * CC;
    const unsigned short* vbp = Vbuf + (size_t)b * CC * SS;

    // Q A-frags for the wave's two 16-row subtiles, loaded once from global
    sh8 aq[2][4];
    #pragma unroll
    for (int m = 0; m < 2; ++m) {
        const unsigned short* qp = Qbuf + ((size_t)b * SS + qbase + m * 16 + l15) * CC + quad * 8;
        #pragma unroll
        for (int kk = 0; kk < 4; ++kk) aq[m][kk] = *(const sh8*)(qp + 32 * kk);
    }

    // per-lane DMA source offsets (bytes), constant across iterations
    int kGO[4], vGO[4];
    #pragma unroll
    for (int j = 0; j < 4; ++j) {
        const int krow = wave * 16 + j * 4 + (lane >> 4);
        kGO[j] = krow * 256 + (((lane & 15) ^ (krow & 7)) << 4);
        const int vrow = (wave * 4 + j) * 8 + (lane >> 3);
        vGO[j] = vrow * 8192 + (((lane & 7) ^ ((lane >> 3) & 7)) << 4);
    }

    f32x4 oacc[2][8];
    #pragma unroll
    for (int m = 0; m < 2; ++m)
        #pragma unroll
        for (int ct = 0; ct < 8; ++ct) oacc[m][ct] = (f32x4){0.f, 0.f, 0.f, 0.f};
    float lsum[2][4] = {{0.f, 0.f, 0.f, 0.f}, {0.f, 0.f, 0.f, 0.f}};

    // prologue: stage tile 0 into buffer 0
    #pragma unroll
    for (int j = 0; j < 4; ++j) {
        dma16((const char*)kbp + kGO[j], smem + (wave * 4 + j) * 1024);
        dma16((const char*)vbp + vGO[j], smem + 32768 + (wave * 4 + j) * 1024);
    }

    for (int it = 0; it < SS / KT; ++it) {
        unsigned char* kb = smem + ((it & 1) << 14);
        unsigned char* vb = smem + 32768 + ((it & 1) << 14);

        // own DMA for tile `it` drained, then block-wide sync -> tile resident,
        // and everyone is done reading the OTHER buffer (prev iter).
        asm volatile("s_waitcnt vmcnt(0)" ::: "memory");
        __builtin_amdgcn_s_barrier();

        // issue next-tile DMA into the other buffer; overlaps entire compute
        if (it + 1 < SS / KT) {
            unsigned char* kbn = smem + (((it + 1) & 1) << 14);
            unsigned char* vbn = smem + 32768 + (((it + 1) & 1) << 14);
            const char* gk = (const char*)kbp + (size_t)(it + 1) * KT * 256;
            const char* gv = (const char*)vbp + (size_t)(it + 1) * KT * 2;
            #pragma unroll
            for (int j = 0; j < 4; ++j) {
                dma16(gk + kGO[j], kbn + (wave * 4 + j) * 1024);
                dma16(gv + vGO[j], vbn + (wave * 4 + j) * 1024);
            }
        }

        // --- S = Q K^T : 16 K-frag loads, each feeds BOTH q-subtiles ---
        f32x4 sacc[2][4];
        #pragma unroll
        for (int m = 0; m < 2; ++m)
            #pragma unroll
            for (int n = 0; n < 4; ++n) sacc[m][n] = (f32x4){0.f, 0.f, 0.f, 0.f};
        #pragma unroll
        for (int n = 0; n < 4; ++n) {
            #pragma unroll
            for (int kk = 0; kk < 4; ++kk) {
                sh8 kf = *(const sh8*)(kb + (16 * n + l15) * 256
                                          + (((4 * kk + quad) ^ (l15 & 7)) << 4));
                sacc[0][n] = __builtin_amdgcn_mfma_f32_16x16x32_bf16(aq[0][kk], kf, sacc[0][n], 0, 0, 0);
                sacc[1][n] = __builtin_amdgcn_mfma_f32_16x16x32_bf16(aq[1][kk], kf, sacc[1][n], 0, 0, 0);
            }
        }

        // --- unnormalized softmax -> swizzled P (row*128 + (chunk^(row&7))*16) ---
        #pragma unroll
        for (int m = 0; m < 2; ++m)
            #pragma unroll
            for (int n = 0; n < 4; ++n)
                #pragma unroll
                for (int r = 0; r < 4; ++r) {
                    float p = __expf(sacc[m][n][r] * SCALE);
                    lsum[m][r] += p;
                    const int row = m * 16 + quad * 4 + r, col = 16 * n + l15;
                    *(unsigned short*)(pw + row * 128
                                       + (((col >> 3) ^ (row & 7)) << 4)
                                       + (col & 7) * 2) = rhu(p);
                }

        // --- PV: per ks, 2 P-frags + 8 V-frags feed 16 MFMA (V reused 2x) ---
        #pragma unroll
        for (int ks = 0; ks < 2; ++ks) {
            sh8 ap0 = *(const sh8*)(pw + l15 * 128
                                       + (((ks * 4 + quad) ^ (l15 & 7)) << 4));
            sh8 ap1 = *(const sh8*)(pw + (16 + l15) * 128
                                       + (((ks * 4 + quad) ^ (l15 & 7)) << 4));
            #pragma unroll
            for (int ct = 0; ct < 8; ++ct) {
                sh8 bv = *(const sh8*)(vb + (16 * ct + l15) * 128
                                          + (((ks * 4 + quad) ^ (l15 & 7)) << 4));
                oacc[0][ct] = __builtin_amdgcn_mfma_f32_16x16x32_bf16(ap0, bv, oacc[0][ct], 0, 0, 0);
                oacc[1][ct] = __builtin_amdgcn_mfma_f32_16x16x32_bf16(ap1, bv, oacc[1][ct], 0, 0, 0);
            }
        }
    }

    // --- row-sum reduction across the 16 lanes of each quad ---
    #pragma unroll
    for (int m = 0; m < 2; ++m)
        #pragma unroll
        for (int r = 0; r < 4; ++r) {
            float v = lsum[m][r];
            #pragma unroll
            for (int s = 8; s >= 1; s >>= 1) v += __shfl_xor(v, s, 64);
            lsum[m][r] = v;
        }

    __syncthreads();   // everyone done with K/V/P before aliasing smem

    // --- epilogue: normalize, residual, coalesced transpose write ---
    float (*oLds)[129] = (float(*)[129])smem;   // 128 x 129 fp32 = 66,048 B
    #pragma unroll
    for (int m = 0; m < 2; ++m)
        #pragma unroll
        for (int ct = 0; ct < 8; ++ct) {
            const int c = 16 * ct + l15;
            #pragma unroll
            for (int r = 0; r < 4; ++r) {
                const int qloc  = wave * 32 + m * 16 + quad * 4 + r;
                const int qglob = qtile * 128 + qloc;
                const float resid = b2f(Qbuf[((size_t)b * SS + qglob) * CC + c]);
                oLds[qloc][c] = oacc[m][ct][r] / lsum[m][r] + resid;
            }
        }
    __syncthreads();
    for (int idx = tid; idx < 128 * 128; idx += 256) {
        const int c = idx >> 7, q = idx & 127;
        out[((size_t)b * CC + c) * SS + qtile * 128 + q] = oLds[q][c];
    }
}

extern "C" void kernel_launch(void* const* d_in, const int* in_sizes, int n_in,
                              void* d_out, int out_size, void* d_ws, size_t ws_size,
                              hipStream_t stream) {
    const float* qimg = (const float*)d_in[0];
    const float* kimg = (const float*)d_in[1];
    const float* vimg = (const float*)d_in[2];
    const float* Wq   = (const float*)d_in[3];
    const float* bq   = (const float*)d_in[4];
    const float* Wk   = (const float*)d_in[5];
    const float* bk   = (const float*)d_in[6];
    float* out = (float*)d_out;

    unsigned short* Qbuf = (unsigned short*)d_ws;                    // 8 MB
    unsigned short* Kbuf = Qbuf + (size_t)BB * SS * CC;              // 8 MB
    unsigned short* Vbuf = Kbuf + (size_t)BB * SS * CC;              // 8 MB
    unsigned short* Wqb  = Vbuf + (size_t)BB * SS * CC;              // 32 KB
    unsigned short* Wkb  = Wqb + CC * CC;                            // 32 KB
    unsigned short* bqb  = Wkb + CC * CC;
    unsigned short* bkb  = bqb + CC;

    cvt_kernel<<<dim3(520), 256, 0, stream>>>(vimg, Wq, Wk, bq, bk,
                                              Vbuf, Wqb, Wkb, bqb, bkb);
    proj_kernel<<<dim3(SS / 64, BB, 2), 256, 0, stream>>>(
        qimg, kimg, Wqb, Wkb, bqb, bkb, Qbuf, Kbuf);
    attn_kernel<<<dim3(BB * (SS / 128)), 256, 0, stream>>>(Qbuf, Kbuf, Vbuf, out);
}

// Round 2
// 209.847 us; speedup vs baseline: 1.1859x; 1.1859x over previous
//
#include <hip/hip_runtime.h>

// Shapes fixed by the reference: B=8, C=128, H=W=64 -> S=4096. All I/O fp32.
#define BB 8
#define CC 128
#define SS 4096
#define KT 64             // kv tile per iteration
#define NSPLIT 2          // KV split factor (flash-style partial softmax)
#define HKV (SS / NSPLIT) // kv tokens per block = 2048
#define SCALE 0.015625f   // 1/sqrt(H*W) = 1/64

typedef __attribute__((ext_vector_type(8))) short sh8;   // 8 bf16 (MFMA A/B frag)
typedef __attribute__((ext_vector_type(4))) float f32x4; // MFMA C/D frag

__device__ __forceinline__ float b2f(unsigned short u) {
    union { unsigned int i; float f; } x; x.i = ((unsigned int)u) << 16; return x.f;
}
__device__ __forceinline__ unsigned short f2b(float f) {  // RNE (used in cvt)
    union { float f; unsigned int i; } x; x.f = f;
    unsigned int r = x.i + 0x7fff + ((x.i >> 16) & 1);
    return (unsigned short)(r >> 16);
}
__device__ __forceinline__ unsigned short rhu(float f) {  // round-half-up, 2 VALU
    union { float f; unsigned int i; } x; x.f = f;
    return (unsigned short)((x.i + 0x8000) >> 16);
}

// async 16B global->LDS DMA (lane i writes lds_base + i*16; LDS base wave-uniform)
__device__ __forceinline__ void dma16(const void* g, void* l) {
    __builtin_amdgcn_global_load_lds((const __attribute__((address_space(1))) void*)g,
                                     (__attribute__((address_space(3))) void*)l,
                                     16, 0, 0);
}

// ---------------------------------------------------------------------------
// cvt: V fp32->bf16 (layout preserved) + W/bias fp32->bf16 (one-time).
// blocks 0..511: V. blocks 512..519: Wq|Wk|bq|bk concat (33024 elems).
// ---------------------------------------------------------------------------
__global__ __launch_bounds__(256) void cvt_kernel(
    const float* __restrict__ vimg,
    const float* __restrict__ Wq, const float* __restrict__ Wk,
    const float* __restrict__ bq, const float* __restrict__ bk,
    unsigned short* __restrict__ Vbuf,
    unsigned short* __restrict__ Wqb, unsigned short* __restrict__ Wkb,
    unsigned short* __restrict__ bqb, unsigned short* __restrict__ bkb)
{
    const int bx = blockIdx.x, tid = threadIdx.x;
    if (bx < 512) {
        const size_t base = (size_t)bx * 8192 + tid * 4;
        #pragma unroll
        for (int it = 0; it < 8; ++it) {
            const size_t i = base + (size_t)it * 1024;
            float4 v = *(const float4*)(vimg + i);
            ushort4 o;
            o.x = f2b(v.x); o.y = f2b(v.y); o.z = f2b(v.z); o.w = f2b(v.w);
            *(ushort4*)(Vbuf + i) = o;
        }
    } else {
        const int w = bx - 512;  // 0..7
        for (int e = w * 256 + tid; e < 33024; e += 2048) {
            float v; unsigned short* dst;
            if (e < 16384)      { v = Wq[e];         dst = Wqb + e; }
            else if (e < 32768) { v = Wk[e - 16384]; dst = Wkb + (e - 16384); }
            else if (e < 32896) { v = bq[e - 32768]; dst = bqb + (e - 32768); }
            else                { v = bk[e - 32896]; dst = bkb + (e - 32896); }
            *dst = f2b(v);
        }
    }
}

// ---------------------------------------------------------------------------
// Projection with LDS-transposed img staging (coalesced float4 global loads).
// outTok[b][s][o] = sum_c img[b][c][s] * W[o][c] + bias[o]
// grid=(64, 8, 2): z=0 -> Q, z=1 -> K.
// ---------------------------------------------------------------------------
__global__ __launch_bounds__(256) void proj_kernel(
    const float* __restrict__ qimg, const float* __restrict__ kimg,
    const unsigned short* __restrict__ Wqb, const unsigned short* __restrict__ Wkb,
    const unsigned short* __restrict__ bqb, const unsigned short* __restrict__ bkb,
    unsigned short* __restrict__ Qbuf, unsigned short* __restrict__ Kbuf)
{
    __shared__ float ilds[128 * 69];   // 128 chans x (64 tokens + 5 pad) = 35,328 B

    const int z = blockIdx.z;
    const float* img = (z == 0) ? qimg : kimg;
    const unsigned short* Wb = (z == 0) ? Wqb : Wkb;
    const unsigned short* bias = (z == 0) ? bqb : bkb;
    unsigned short* outTok = (z == 0) ? Qbuf : Kbuf;

    const int tid  = threadIdx.x;
    const int wave = tid >> 6;
    const int lane = tid & 63;
    const int l15  = lane & 15;
    const int quad = lane >> 4;
    const int b     = blockIdx.y;
    const int stile = blockIdx.x;

    // stage 128x64 fp32 tile, coalesced (64B contiguous per 16 lanes)
    const float* gbase = img + (size_t)b * CC * SS + stile * 64;
    #pragma unroll
    for (int i = 0; i < 8; ++i) {
        const int l = tid + 256 * i;          // 0..2047
        const int row = l >> 4, col = (l & 15) * 4;
        float4 v = *(const float4*)(gbase + (size_t)row * SS + col);
        float* d = ilds + row * 69 + col;
        d[0] = v.x; d[1] = v.y; d[2] = v.z; d[3] = v.w;
    }
    __syncthreads();

    // A-frags from LDS: A[m=l15][k=32kk+quad*8+j] = img[c=k][token]
    const int tcol = wave * 16 + l15;
    sh8 a[4];
    #pragma unroll
    for (int kk = 0; kk < 4; ++kk)
        #pragma unroll
        for (int j = 0; j < 8; ++j)
            a[kk][j] = (short)rhu(ilds[(32 * kk + quad * 8 + j) * 69 + tcol]);

    f32x4 acc[8];
    #pragma unroll
    for (int nt = 0; nt < 8; ++nt) acc[nt] = (f32x4){0.f, 0.f, 0.f, 0.f};

    #pragma unroll
    for (int nt = 0; nt < 8; ++nt) {
        const unsigned short* wp = Wb + (size_t)(16 * nt + l15) * CC + quad * 8;
        #pragma unroll
        for (int kk = 0; kk < 4; ++kk) {
            sh8 bf = *(const sh8*)(wp + 32 * kk);
            acc[nt] = __builtin_amdgcn_mfma_f32_16x16x32_bf16(a[kk], bf, acc[nt], 0, 0, 0);
        }
    }

    #pragma unroll
    for (int nt = 0; nt < 8; ++nt) {
        const int o = 16 * nt + l15;
        const float bv = b2f(bias[o]);
        #pragma unroll
        for (int r = 0; r < 4; ++r) {
            const int s = stile * 64 + wave * 16 + quad * 4 + r;
            outTok[((size_t)b * SS + s) * CC + o] = f2b(acc[nt][r] + bv);
        }
    }
}

// ---------------------------------------------------------------------------
// Flash attention, M=32 q/wave, split-KV=2 -> grid 512 = 2 blocks/CU
// (2 waves/SIMD restores cross-wave MFMA/VALU overlap lost in round 1).
// Block: 4 waves x 32 q = 128 q, iterates over 2048 kv (32 tiles of 64).
// LDS (65,536 B -> 2 blocks/CU = 128/160 KB):
//   [0,16384)      K buf0 : 64 rows(token) x 256 B, chunk swizzle ^(row&7)
//   [16384,32768)  K buf1   (double-buffered: DMA issued at barrier (a))
//   [32768,49152)  V      : 128 rows(chan) x 128 B, single-buffered
//   [49152,65536)  P      : 4 waves x (32 rows x 128 B), chunk swizzle
//   epilogue: oT ushort[128][136] (34,816 B) aliases front after final (b).
// Per iter: sync(a: all DMAs landed) -> DMA K[it+1]->other K buf ->
//   QK (16 loads/32 MFMA, K frags reused by both q-subtiles) -> softmax/P ->
//   PV ks0 (LDS) + preload ks1 V frags -> sync(b: V reads drained) ->
//   DMA V[it+1] -> PV ks1 (V from regs, P re-read from stable LDS).
// Output: UNNORMALIZED O (bf16) + row-sums L (f32); combine_kernel merges.
// ---------------------------------------------------------------------------
__global__ __launch_bounds__(256, 2) void attn_kernel(
    const unsigned short* __restrict__ Qbuf,  // (B,S,C) bf16 token-major
    const unsigned short* __restrict__ Kbuf,  // (B,S,C) bf16 token-major
    const unsigned short* __restrict__ Vbuf,  // (B,C,S) bf16 channel-major
    unsigned short* __restrict__ Opart,       // (NSPLIT,B,C,S) bf16 partial O
    float* __restrict__ Lsum)                 // (NSPLIT,B,S) f32 partial sums
{
    __shared__ __align__(16) unsigned char smem[65536];
    unsigned char* vb = smem + 32768;

    const int tid  = threadIdx.x;
    const int wave = tid >> 6;
    const int lane = tid & 63;
    const int l15  = lane & 15;
    const int quad = lane >> 4;
    const int wgid = blockIdx.x;
    const int b    = wgid & 7;          // batch == XCD (L2 holds one batch's K/V)
    const int half = (wgid >> 3) & 1;   // KV half; CU-pair = same half, qt+16 apart
    const int qt   = wgid >> 4;         // 0..31, 128 queries each
    const int qbase = qt * 128 + wave * 32;
    const int tok0  = half * HKV;

    unsigned char* pw = smem + 49152 + wave * 4096;  // this wave's P (32 x 128 B)

    const unsigned short* kbp = Kbuf + (size_t)b * SS * CC;
    const unsigned short* vbp = Vbuf + (size_t)b * CC * SS;

    // Q A-frags for the wave's two 16-row subtiles, loaded once from global
    sh8 aq[2][4];
    #pragma unroll
    for (int m = 0; m < 2; ++m) {
        const unsigned short* qp = Qbuf + ((size_t)b * SS + qbase + m * 16 + l15) * CC + quad * 8;
        #pragma unroll
        for (int kk = 0; kk < 4; ++kk) aq[m][kk] = *(const sh8*)(qp + 32 * kk);
    }

    // per-lane DMA source offsets (bytes), constant across iterations
    int kGO[4], vGO[4];
    #pragma unroll
    for (int j = 0; j < 4; ++j) {
        const int krow = wave * 16 + j * 4 + (lane >> 4);
        kGO[j] = krow * 256 + (((lane & 15) ^ (krow & 7)) << 4);
        const int vrow = (wave * 4 + j) * 8 + (lane >> 3);
        vGO[j] = vrow * 8192 + (((lane & 7) ^ ((lane >> 3) & 7)) << 4);
    }

    f32x4 oacc[2][8];
    #pragma unroll
    for (int m = 0; m < 2; ++m)
        #pragma unroll
        for (int ct = 0; ct < 8; ++ct) oacc[m][ct] = (f32x4){0.f, 0.f, 0.f, 0.f};
    float lsum[2][4] = {{0.f, 0.f, 0.f, 0.f}, {0.f, 0.f, 0.f, 0.f}};

    // prologue: stage K[0] -> buf0, V[0]
    {
        const char* gk = (const char*)kbp + (size_t)tok0 * 256;
        const char* gv = (const char*)vbp + (size_t)tok0 * 2;
        #pragma unroll
        for (int j = 0; j < 4; ++j) {
            dma16(gk + kGO[j], smem + (wave * 4 + j) * 1024);
            dma16(gv + vGO[j], vb + (wave * 4 + j) * 1024);
        }
    }

    for (int it = 0; it < HKV / KT; ++it) {
        unsigned char* kb = smem + ((it & 1) << 14);

        __syncthreads();   // (a) own DMA drained (K[it], V[it]) + all waves synced

        // K double-buffer: issue next K tile now; lands by next (a)
        if (it + 1 < HKV / KT) {
            const char* gk = (const char*)kbp + (size_t)(tok0 + (it + 1) * KT) * 256;
            unsigned char* kbn = smem + (((it + 1) & 1) << 14);
            #pragma unroll
            for (int j = 0; j < 4; ++j) dma16(gk + kGO[j], kbn + (wave * 4 + j) * 1024);
        }

        // --- S = Q K^T : 16 K-frag loads, each feeds BOTH q-subtiles ---
        f32x4 sacc[2][4];
        #pragma unroll
        for (int m = 0; m < 2; ++m)
            #pragma unroll
            for (int n = 0; n < 4; ++n) sacc[m][n] = (f32x4){0.f, 0.f, 0.f, 0.f};
        __builtin_amdgcn_s_setprio(1);
        #pragma unroll
        for (int n = 0; n < 4; ++n) {
            #pragma unroll
            for (int kk = 0; kk < 4; ++kk) {
                sh8 kf = *(const sh8*)(kb + (16 * n + l15) * 256
                                          + (((4 * kk + quad) ^ (l15 & 7)) << 4));
                sacc[0][n] = __builtin_amdgcn_mfma_f32_16x16x32_bf16(aq[0][kk], kf, sacc[0][n], 0, 0, 0);
                sacc[1][n] = __builtin_amdgcn_mfma_f32_16x16x32_bf16(aq[1][kk], kf, sacc[1][n], 0, 0, 0);
            }
        }
        __builtin_amdgcn_s_setprio(0);

        // --- unnormalized softmax -> swizzled P (row*128 + (chunk^(row&7))*16) ---
        #pragma unroll
        for (int m = 0; m < 2; ++m)
            #pragma unroll
            for (int n = 0; n < 4; ++n)
                #pragma unroll
                for (int r = 0; r < 4; ++r) {
                    float p = __expf(sacc[m][n][r] * SCALE);
                    lsum[m][r] += p;
                    const int row = m * 16 + quad * 4 + r, col = 16 * n + l15;
                    *(unsigned short*)(pw + row * 128
                                       + (((col >> 3) ^ (row & 7)) << 4)
                                       + (col & 7) * 2) = rhu(p);
                }

        // --- PV ks=0 from LDS (P chunk = quad, V chunk = quad) ---
        {
            sh8 ap0 = *(const sh8*)(pw + l15 * 128 + ((quad ^ (l15 & 7)) << 4));
            sh8 ap1 = *(const sh8*)(pw + (16 + l15) * 128 + ((quad ^ (l15 & 7)) << 4));
            __builtin_amdgcn_s_setprio(1);
            #pragma unroll
            for (int ct = 0; ct < 8; ++ct) {
                sh8 bv = *(const sh8*)(vb + (16 * ct + l15) * 128
                                          + ((quad ^ (l15 & 7)) << 4));
                oacc[0][ct] = __builtin_amdgcn_mfma_f32_16x16x32_bf16(ap0, bv, oacc[0][ct], 0, 0, 0);
                oacc[1][ct] = __builtin_amdgcn_mfma_f32_16x16x32_bf16(ap1, bv, oacc[1][ct], 0, 0, 0);
            }
            __builtin_amdgcn_s_setprio(0);
        }

        // --- preload ks=1 V frags to regs (V buffer is overwritten after (b)) ---
        sh8 vv[8];
        #pragma unroll
        for (int ct = 0; ct < 8; ++ct)
            vv[ct] = *(const sh8*)(vb + (16 * ct + l15) * 128
                                      + (((4 + quad) ^ (l15 & 7)) << 4));

        __syncthreads();   // (b) all waves' V/P read data landed in regs

        // single-buffered V: overwrite is now safe; lands by next (a)
        if (it + 1 < HKV / KT) {
            const char* gv = (const char*)vbp + (size_t)(tok0 + (it + 1) * KT) * 2;
            #pragma unroll
            for (int j = 0; j < 4; ++j) dma16(gv + vGO[j], vb + (wave * 4 + j) * 1024);
        }

        // --- PV ks=1: V from regs, P re-read from stable per-wave LDS region ---
        {
            sh8 ap0 = *(const sh8*)(pw + l15 * 128 + (((4 + quad) ^ (l15 & 7)) << 4));
            sh8 ap1 = *(const sh8*)(pw + (16 + l15) * 128 + (((4 + quad) ^ (l15 & 7)) << 4));
            __builtin_amdgcn_s_setprio(1);
            #pragma unroll
            for (int ct = 0; ct < 8; ++ct) {
                oacc[0][ct] = __builtin_amdgcn_mfma_f32_16x16x32_bf16(ap0, vv[ct], oacc[0][ct], 0, 0, 0);
                oacc[1][ct] = __builtin_amdgcn_mfma_f32_16x16x32_bf16(ap1, vv[ct], oacc[1][ct], 0, 0, 0);
            }
            __builtin_amdgcn_s_setprio(0);
        }
    }

    // --- row-sum reduction across the 16 lanes of each quad ---
    #pragma unroll
    for (int m = 0; m < 2; ++m)
        #pragma unroll
        for (int r = 0; r < 4; ++r) {
            float v = lsum[m][r];
            #pragma unroll
            for (int s = 8; s >= 1; s >>= 1) v += __shfl_xor(v, s, 64);
            lsum[m][r] = v;
        }

    // --- epilogue: unnormalized O -> bf16, LDS transpose, coalesced store ---
    // safe to overwrite K/V/P: all LDS reads completed before last (b)/in regs
    unsigned short* oT = (unsigned short*)smem;   // [128 c][136 pad] ushorts
    #pragma unroll
    for (int m = 0; m < 2; ++m)
        #pragma unroll
        for (int ct = 0; ct < 8; ++ct) {
            const int c  = 16 * ct + l15;
            const int q0 = wave * 32 + m * 16 + quad * 4;
            ushort4 o;
            o.x = rhu(oacc[m][ct][0]); o.y = rhu(oacc[m][ct][1]);
            o.z = rhu(oacc[m][ct][2]); o.w = rhu(oacc[m][ct][3]);
            *(ushort4*)(oT + c * 136 + q0) = o;
        }

    // lsum: one lane per quad writes its 8 row-sums
    if (l15 == 0) {
        float* lp = Lsum + ((size_t)half * BB + b) * SS + qt * 128;
        #pragma unroll
        for (int m = 0; m < 2; ++m)
            #pragma unroll
            for (int r = 0; r < 4; ++r)
                lp[wave * 32 + m * 16 + quad * 4 + r] = lsum[m][r];
    }
    __syncthreads();

    unsigned short* op = Opart + ((size_t)half * BB + b) * CC * SS + qt * 128;
    #pragma unroll
    for (int i = 0; i < 16; ++i) {
        const int idx = tid + 256 * i;        // 0..4095
        const int c = idx >> 5, q4 = (idx & 31) * 4;
        *(ushort4*)(op + (size_t)c * SS + q4) = *(const ushort4*)(oT + c * 136 + q4);
    }
}

// ---------------------------------------------------------------------------
// combine: out[b][c][s] = (O0+O1)/(L0+L1) + resid(Qbuf[b][s][c]).
// grid (64,8), 256 thr. Lanes span s (coalesced fp32 stores); resid reads are
// 2B stride-256B but L1-resident (16 KB row footprint, reused across c).
// ---------------------------------------------------------------------------
__global__ __launch_bounds__(256) void combine_kernel(
    const unsigned short* __restrict__ Qbuf,
    const unsigned short* __restrict__ Opart,
    const float* __restrict__ Lsum,
    float* __restrict__ out)
{
    const int b = blockIdx.y, st = blockIdx.x, tid = threadIdx.x;
    const int s0   = st * 64 + (tid & 15) * 4;   // 4 consecutive tokens
    const int coff = tid >> 4;                   // 16 channel phases

    float4 l0 = *(const float4*)(Lsum + (size_t)b * SS + s0);
    float4 l1 = *(const float4*)(Lsum + ((size_t)BB + b) * SS + s0);
    float rinv[4];
    rinv[0] = 1.f / (l0.x + l1.x); rinv[1] = 1.f / (l0.y + l1.y);
    rinv[2] = 1.f / (l0.z + l1.z); rinv[3] = 1.f / (l0.w + l1.w);

    const unsigned short* qb = Qbuf + (size_t)b * SS * CC;
    for (int c = coff; c < CC; c += 16) {
        const size_t po = ((size_t)b * CC + c) * SS + s0;
        ushort4 p0 = *(const ushort4*)(Opart + po);
        ushort4 p1 = *(const ushort4*)(Opart + (size_t)BB * CC * SS + po);
        float4 o;
        o.x = (b2f(p0.x) + b2f(p1.x)) * rinv[0] + b2f(qb[(size_t)(s0 + 0) * CC + c]);
        o.y = (b2f(p0.y) + b2f(p1.y)) * rinv[1] + b2f(qb[(size_t)(s0 + 1) * CC + c]);
        o.z = (b2f(p0.z) + b2f(p1.z)) * rinv[2] + b2f(qb[(size_t)(s0 + 2) * CC + c]);
        o.w = (b2f(p0.w) + b2f(p1.w)) * rinv[3] + b2f(qb[(size_t)(s0 + 3) * CC + c]);
        *(float4*)(out + po) = o;
    }
}

extern "C" void kernel_launch(void* const* d_in, const int* in_sizes, int n_in,
                              void* d_out, int out_size, void* d_ws, size_t ws_size,
                              hipStream_t stream) {
    const float* qimg = (const float*)d_in[0];
    const float* kimg = (const float*)d_in[1];
    const float* vimg = (const float*)d_in[2];
    const float* Wq   = (const float*)d_in[3];
    const float* bq   = (const float*)d_in[4];
    const float* Wk   = (const float*)d_in[5];
    const float* bk   = (const float*)d_in[6];
    float* out = (float*)d_out;

    // workspace map (needs ~42.3 MB):
    unsigned short* Qbuf = (unsigned short*)d_ws;                    // 8 MB
    unsigned short* Kbuf = Qbuf + (size_t)BB * SS * CC;              // 8 MB
    unsigned short* Vbuf = Kbuf + (size_t)BB * SS * CC;              // 8 MB
    unsigned short* Wqb  = Vbuf + (size_t)BB * SS * CC;              // 32 KB
    unsigned short* Wkb  = Wqb + CC * CC;                            // 32 KB
    unsigned short* bqb  = Wkb + CC * CC;
    unsigned short* bkb  = bqb + CC;
    unsigned short* Opart = bkb + CC;                                // 16 MB bf16
    float* Lsum = (float*)(Opart + (size_t)NSPLIT * BB * CC * SS);   // 256 KB

    cvt_kernel<<<dim3(520), 256, 0, stream>>>(vimg, Wq, Wk, bq, bk,
                                              Vbuf, Wqb, Wkb, bqb, bkb);
    proj_kernel<<<dim3(SS / 64, BB, 2), 256, 0, stream>>>(
        qimg, kimg, Wqb, Wkb, bqb, bkb, Qbuf, Kbuf);
    attn_kernel<<<dim3(NSPLIT * BB * (SS / 128)), 256, 0, stream>>>(
        Qbuf, Kbuf, Vbuf, Opart, Lsum);
    combine_kernel<<<dim3(SS / 64, BB), 256, 0, stream>>>(Qbuf, Opart, Lsum, out);
}